// Round 5
// baseline (144.878 us; speedup 1.0000x reference)
//
#include <hip/hip_runtime.h>
#include <cstdint>

#define D_MODEL 128
#define D_EMB   64
#define MAXLEN  32
#define NB      2
#define NMSA    4
#define LL      768
#define NREL    (2 * MAXLEN - 1)

#define FILL_BLOCKS  2048
#define FILL_THREADS 256
#define TOTAL_Q4     (NB * LL * LL * (D_MODEL / 4))      // 37748736 float4s
#define NITER        (TOTAL_Q4 / (FILL_BLOCKS * FILL_THREADS))  // 72 exactly

typedef float f32x4 __attribute__((ext_vector_type(4)));

// Fused prep:
//  blocks 0 .. NB*LL-1 : P[bi][d] = sum_k e[bi,k] * W_proj[k][d]
//                        Q[bi][d] = sum_k e[bi,k] * W_proj[64+k][d]
//  block  NB*LL        : R[r][d]  = W_pos[r][d] + b_pos[d] + b_proj[d]
__global__ void prep_kernel(const int* __restrict__ msa_tokens,
                            const float* __restrict__ emb,
                            const float* __restrict__ W_proj,
                            const float* __restrict__ b_proj,
                            const float* __restrict__ W_pos,
                            const float* __restrict__ b_pos,
                            float* __restrict__ P, float* __restrict__ Q,
                            float* __restrict__ R) {
    int bi = blockIdx.x;
    int d  = threadIdx.x;           // 0 .. 127
    if (bi == NB * LL) {
        float bias = b_pos[d] + b_proj[d];
        #pragma unroll
        for (int r = 0; r < NREL; ++r) {
            R[r * D_MODEL + d] = W_pos[r * D_MODEL + d] + bias;
        }
        return;
    }
    int b = bi / LL;
    int i = bi - b * LL;
    __shared__ float e[D_EMB];
    int tok = msa_tokens[(b * NMSA + 0) * LL + i];
    if (d < D_EMB) {
        e[d] = (tok != 0) ? emb[tok * D_EMB + d] : 0.0f;
    }
    __syncthreads();
    float p = 0.f, q = 0.f;
    #pragma unroll
    for (int k = 0; k < D_EMB; ++k) {
        float ek = e[k];
        p = fmaf(ek, W_proj[k * D_MODEL + d], p);
        q = fmaf(ek, W_proj[(D_EMB + k) * D_MODEL + d], q);
    }
    P[bi * D_MODEL + d] = p;
    Q[bi * D_MODEL + d] = q;
}

// out[b,i,j,d] = P[b,i,d] + Q[b,j,d] + R[clip(i-j,-31,31)+31, d]
// fillBuffer-style flat grid-stride: the device's active store window at any
// instant is ~8MB and marches linearly -> max DRAM page-hit rate for the
// NT-store stream. All reads are L1/L2-resident.
__global__ __launch_bounds__(FILL_THREADS) void fill_kernel(
        const float* __restrict__ P, const float* __restrict__ Q,
        const float* __restrict__ R, float* __restrict__ out) {
    const unsigned g = blockIdx.x * FILL_THREADS + threadIdx.x;
    const f32x4* P4 = reinterpret_cast<const f32x4*>(P);
    const f32x4* Q4 = reinterpret_cast<const f32x4*>(Q);
    const f32x4* R4 = reinterpret_cast<const f32x4*>(R);
    f32x4* o4 = reinterpret_cast<f32x4*>(out);

    #pragma unroll 4
    for (int s = 0; s < NITER; ++s) {
        unsigned idx = g + (unsigned)s * (FILL_BLOCKS * FILL_THREADS);
        unsigned d4  = idx & 31;          // float4 within the 128-dim channel
        unsigned row = idx >> 5;          // bi*LL + j
        unsigned bi  = row / (unsigned)LL;
        unsigned j   = row - bi * (unsigned)LL;
        int      isb = bi >= (unsigned)LL;
        int      i   = (int)bi - (isb ? LL : 0);

        int rel = i - (int)j;
        rel = rel > (MAXLEN - 1) ? (MAXLEN - 1) : rel;
        rel = rel < -(MAXLEN - 1) ? -(MAXLEN - 1) : rel;
        rel += MAXLEN - 1;

        f32x4 p = P4[bi * 32 + d4];
        f32x4 q = Q4[((isb ? (unsigned)LL : 0u) + j) * 32 + d4];
        f32x4 r = R4[(unsigned)rel * 32 + d4];
        f32x4 o = p + q + r;
        __builtin_nontemporal_store(o, &o4[(size_t)idx]);
    }
}

extern "C" void kernel_launch(void* const* d_in, const int* in_sizes, int n_in,
                              void* d_out, int out_size, void* d_ws, size_t ws_size,
                              hipStream_t stream) {
    const int*   msa    = (const int*)d_in[0];
    const float* emb    = (const float*)d_in[1];
    const float* W_proj = (const float*)d_in[2];
    const float* b_proj = (const float*)d_in[3];
    const float* W_pos  = (const float*)d_in[4];
    const float* b_pos  = (const float*)d_in[5];
    float* out = (float*)d_out;

    float* P = (float*)d_ws;                       // NB*LL*128 floats
    float* Q = P + (size_t)NB * LL * D_MODEL;      // NB*LL*128 floats
    float* R = Q + (size_t)NB * LL * D_MODEL;      // NREL*128 floats

    prep_kernel<<<NB * LL + 1, D_MODEL, 0, stream>>>(msa, emb, W_proj, b_proj,
                                                     W_pos, b_pos, P, Q, R);
    fill_kernel<<<FILL_BLOCKS, FILL_THREADS, 0, stream>>>(P, Q, R, out);
}

// Round 6
// 127.785 us; speedup vs baseline: 1.1338x; 1.1338x over previous
//
#include <hip/hip_runtime.h>
#include <cstdint>

#define D_MODEL 128
#define D_EMB   64
#define MAXLEN  32
#define NB      2
#define NMSA    4
#define LL      768
#define JCHUNK  128   // j's per block in fill kernel
#define NREL    (2 * MAXLEN - 1)

typedef float f32x4 __attribute__((ext_vector_type(4)));

// Fused prep:
//  blocks 0 .. NB*LL-1 : P[bi][d] = sum_k e[bi,k] * W_proj[k][d]
//                        Q[bi][d] = sum_k e[bi,k] * W_proj[64+k][d]
//  block  NB*LL        : R[r][d]  = W_pos[r][d] + b_pos[d] + b_proj[d]
__global__ void prep_kernel(const int* __restrict__ msa_tokens,
                            const float* __restrict__ emb,
                            const float* __restrict__ W_proj,
                            const float* __restrict__ b_proj,
                            const float* __restrict__ W_pos,
                            const float* __restrict__ b_pos,
                            float* __restrict__ P, float* __restrict__ Q,
                            float* __restrict__ R) {
    int bi = blockIdx.x;
    int d  = threadIdx.x;           // 0 .. 127
    if (bi == NB * LL) {
        float bias = b_pos[d] + b_proj[d];
        #pragma unroll
        for (int r = 0; r < NREL; ++r) {
            R[r * D_MODEL + d] = W_pos[r * D_MODEL + d] + bias;
        }
        return;
    }
    int b = bi / LL;
    int i = bi - b * LL;
    __shared__ float e[D_EMB];
    int tok = msa_tokens[(b * NMSA + 0) * LL + i];
    if (d < D_EMB) {
        e[d] = (tok != 0) ? emb[tok * D_EMB + d] : 0.0f;
    }
    __syncthreads();
    float p = 0.f, q = 0.f;
    #pragma unroll
    for (int k = 0; k < D_EMB; ++k) {
        float ek = e[k];
        p = fmaf(ek, W_proj[k * D_MODEL + d], p);
        q = fmaf(ek, W_proj[(D_EMB + k) * D_MODEL + d], q);
    }
    P[bi * D_MODEL + d] = p;
    Q[bi * D_MODEL + d] = q;
}

// out[b,i,j,d] = P[b,i,d] + Q[b,j,d] + R[clip(i-j,-31,31)+31, d]
// 64KB LDS ballast caps residency at 2 blocks/CU (8 waves/CU) so the device
// sustains ~512 long contiguous NT-store streams (fillBuffer operates at
// ~10% occupancy and hits 6.7 TB/s) instead of ~9000 page-thrashing ones.
__global__ __launch_bounds__(256) void fill_kernel(
        const float* __restrict__ P, const float* __restrict__ Q,
        const float* __restrict__ R, float* __restrict__ out) {
    volatile __shared__ float ballast[16384];   // 64 KB -> 2 blocks/CU
    ballast[threadIdx.x] = 0.0f;

    int bi    = blockIdx.y;         // b*LL + i
    int b     = bi / LL;
    int i     = bi - b * LL;
    int jbase = blockIdx.x * JCHUNK;
    int t     = threadIdx.x;
    int d4    = t & 31;             // which float4 of the 128-dim channel
    int jo    = t >> 5;             // 0..7

    const f32x4* P4 = reinterpret_cast<const f32x4*>(P);
    const f32x4* Qb = reinterpret_cast<const f32x4*>(Q + (size_t)b * LL * D_MODEL);
    const f32x4* R4 = reinterpret_cast<const f32x4*>(R);
    f32x4* orow = reinterpret_cast<f32x4*>(out + ((size_t)bi * LL + jbase) * D_MODEL);

    f32x4 p = P4[(size_t)bi * 32 + d4];

    #pragma unroll
    for (int jj = 0; jj < JCHUNK; jj += 8) {
        int j = jbase + jj + jo;
        int rel = i - j;
        rel = rel > (MAXLEN - 1) ? (MAXLEN - 1) : rel;
        rel = rel < -(MAXLEN - 1) ? -(MAXLEN - 1) : rel;
        rel += MAXLEN - 1;

        f32x4 q = Qb[(size_t)j * 32 + d4];
        f32x4 r = R4[rel * 32 + d4];
        f32x4 o = p + q + r;
        __builtin_nontemporal_store(o, &orow[(size_t)(jj + jo) * 32 + d4]);
    }
}

extern "C" void kernel_launch(void* const* d_in, const int* in_sizes, int n_in,
                              void* d_out, int out_size, void* d_ws, size_t ws_size,
                              hipStream_t stream) {
    const int*   msa    = (const int*)d_in[0];
    const float* emb    = (const float*)d_in[1];
    const float* W_proj = (const float*)d_in[2];
    const float* b_proj = (const float*)d_in[3];
    const float* W_pos  = (const float*)d_in[4];
    const float* b_pos  = (const float*)d_in[5];
    float* out = (float*)d_out;

    float* P = (float*)d_ws;                       // NB*LL*128 floats
    float* Q = P + (size_t)NB * LL * D_MODEL;      // NB*LL*128 floats
    float* R = Q + (size_t)NB * LL * D_MODEL;      // NREL*128 floats

    prep_kernel<<<NB * LL + 1, D_MODEL, 0, stream>>>(msa, emb, W_proj, b_proj,
                                                     W_pos, b_pos, P, Q, R);
    fill_kernel<<<dim3(LL / JCHUNK, NB * LL), 256, 0, stream>>>(P, Q, R, out);
}

// Round 7
// 121.165 us; speedup vs baseline: 1.1957x; 1.0546x over previous
//
#include <hip/hip_runtime.h>
#include <cstdint>

#define D_MODEL 128
#define D_EMB   64
#define MAXLEN  32
#define NB      2
#define NMSA    4
#define LL      768
#define JCHUNK  256   // j's per block in fill kernel (128KB contiguous stream)
#define NREL    (2 * MAXLEN - 1)

typedef float f32x4 __attribute__((ext_vector_type(4)));

// Fused prep:
//  blocks 0 .. NB*LL-1 : P[bi][d] = sum_k e[bi,k] * W_proj[k][d]
//                        Q[bi][d] = sum_k e[bi,k] * W_proj[64+k][d]
//  block  NB*LL        : R[r][d]  = W_pos[r][d] + b_pos[d] + b_proj[d]
__global__ void prep_kernel(const int* __restrict__ msa_tokens,
                            const float* __restrict__ emb,
                            const float* __restrict__ W_proj,
                            const float* __restrict__ b_proj,
                            const float* __restrict__ W_pos,
                            const float* __restrict__ b_pos,
                            float* __restrict__ P, float* __restrict__ Q,
                            float* __restrict__ R) {
    int bi = blockIdx.x;
    int d  = threadIdx.x;           // 0 .. 127
    if (bi == NB * LL) {
        float bias = b_pos[d] + b_proj[d];
        #pragma unroll
        for (int r = 0; r < NREL; ++r) {
            R[r * D_MODEL + d] = W_pos[r * D_MODEL + d] + bias;
        }
        return;
    }
    int b = bi / LL;
    int i = bi - b * LL;
    __shared__ float e[D_EMB];
    int tok = msa_tokens[(b * NMSA + 0) * LL + i];
    if (d < D_EMB) {
        e[d] = (tok != 0) ? emb[tok * D_EMB + d] : 0.0f;
    }
    __syncthreads();
    float p = 0.f, q = 0.f;
    #pragma unroll
    for (int k = 0; k < D_EMB; ++k) {
        float ek = e[k];
        p = fmaf(ek, W_proj[k * D_MODEL + d], p);
        q = fmaf(ek, W_proj[(D_EMB + k) * D_MODEL + d], q);
    }
    P[bi * D_MODEL + d] = p;
    Q[bi * D_MODEL + d] = q;
}

// out[b,i,j,d] = P[b,i,d] + Q[b,j,d] + R[clip(i-j,-31,31)+31, d]
// 100KB LDS ballast caps residency at 1 block/CU (4 waves/CU, ~256 active
// NT-store streams of 128KB each) — fillBuffer's regime (~3.5 waves/CU,
// 6.7 TB/s). R6 measured: 8 waves/CU beat 36 waves/CU; this is the endpoint.
__global__ __launch_bounds__(256) void fill_kernel(
        const float* __restrict__ P, const float* __restrict__ Q,
        const float* __restrict__ R, float* __restrict__ out) {
    volatile __shared__ float ballast[25600];   // 100 KB -> 1 block/CU
    ballast[threadIdx.x] = 0.0f;

    int bi    = blockIdx.y;         // b*LL + i
    int b     = bi / LL;
    int i     = bi - b * LL;
    int jbase = blockIdx.x * JCHUNK;
    int t     = threadIdx.x;
    int d4    = t & 31;             // which float4 of the 128-dim channel
    int jo    = t >> 5;             // 0..7

    const f32x4* P4 = reinterpret_cast<const f32x4*>(P);
    const f32x4* Qb = reinterpret_cast<const f32x4*>(Q + (size_t)b * LL * D_MODEL);
    const f32x4* R4 = reinterpret_cast<const f32x4*>(R);
    f32x4* orow = reinterpret_cast<f32x4*>(out + ((size_t)bi * LL + jbase) * D_MODEL);

    f32x4 p = P4[(size_t)bi * 32 + d4];

    #pragma unroll
    for (int jj = 0; jj < JCHUNK; jj += 8) {
        int j = jbase + jj + jo;
        int rel = i - j;
        rel = rel > (MAXLEN - 1) ? (MAXLEN - 1) : rel;
        rel = rel < -(MAXLEN - 1) ? -(MAXLEN - 1) : rel;
        rel += MAXLEN - 1;

        f32x4 q = Qb[(size_t)j * 32 + d4];
        f32x4 r = R4[rel * 32 + d4];
        f32x4 o = p + q + r;
        __builtin_nontemporal_store(o, &orow[(size_t)(jj + jo) * 32 + d4]);
    }
}

extern "C" void kernel_launch(void* const* d_in, const int* in_sizes, int n_in,
                              void* d_out, int out_size, void* d_ws, size_t ws_size,
                              hipStream_t stream) {
    const int*   msa    = (const int*)d_in[0];
    const float* emb    = (const float*)d_in[1];
    const float* W_proj = (const float*)d_in[2];
    const float* b_proj = (const float*)d_in[3];
    const float* W_pos  = (const float*)d_in[4];
    const float* b_pos  = (const float*)d_in[5];
    float* out = (float*)d_out;

    float* P = (float*)d_ws;                       // NB*LL*128 floats
    float* Q = P + (size_t)NB * LL * D_MODEL;      // NB*LL*128 floats
    float* R = Q + (size_t)NB * LL * D_MODEL;      // NREL*128 floats

    prep_kernel<<<NB * LL + 1, D_MODEL, 0, stream>>>(msa, emb, W_proj, b_proj,
                                                     W_pos, b_pos, P, Q, R);
    fill_kernel<<<dim3(LL / JCHUNK, NB * LL), 256, 0, stream>>>(P, Q, R, out);
}